// Round 2
// baseline (1576.643 us; speedup 1.0000x reference)
//
#include <hip/hip_runtime.h>
#include <hip/hip_bf16.h>

#define RES   100
#define ITERS 1000
#define SLOTP 128            // floats per LDS boundary-row slot
#define NGROUPS (ITERS / 4)  // 250 groups of 4 steps (cross-block halo depth 4)

typedef float vf2 __attribute__((ext_vector_type(2)));

__device__ __forceinline__ vf2 mk2(float a, float b) { vf2 r; r.x = a; r.y = b; return r; }

// ---------------- fused MLP layers 1-3 ----------------
__global__ __launch_bounds__(256) void mlp123(const float* __restrict__ pores,
                                              const float* __restrict__ W1, const float* __restrict__ b1,
                                              const float* __restrict__ W2, const float* __restrict__ b2,
                                              const float* __restrict__ W3, const float* __restrict__ b3,
                                              float* __restrict__ x3out) {
    __shared__ float x1[128];
    __shared__ float x2[256];
    const int s = blockIdx.x, tid = threadIdx.x;

    if (tid < 128) {
        float acc = b1[tid];
#pragma unroll
        for (int k = 0; k < 25; ++k)
            acc = fmaf(pores[s * 25 + k], W1[k * 128 + tid], acc);
        x1[tid] = fmaxf(acc, 0.0f);
    }
    __syncthreads();

    {
        float acc = b2[tid];
#pragma unroll 8
        for (int k = 0; k < 128; ++k)
            acc = fmaf(x1[k], W2[k * 256 + tid], acc);
        x2[tid] = fmaxf(acc, 0.0f);
    }
    __syncthreads();

    {
        float a0 = b3[tid], a1 = b3[tid + 256];
#pragma unroll 8
        for (int k = 0; k < 256; ++k) {
            float xv = x2[k];
            a0 = fmaf(xv, W3[k * 512 + tid],       a0);
            a1 = fmaf(xv, W3[k * 512 + tid + 256], a1);
        }
        x3out[s * 512 + tid]       = fmaxf(a0, 0.0f);
        x3out[s * 512 + tid + 256] = fmaxf(a1, 0.0f);
    }
}

// ---------------- layer 4: gen + residual + clamp, ILP-pipelined ----------------
__global__ __launch_bounds__(256) void fc4_fused(const float* __restrict__ X3,
                                                 const float* __restrict__ W4,
                                                 const float* __restrict__ b4,
                                                 const float* __restrict__ pores,
                                                 float* __restrict__ cond) {
    const int j = blockIdx.x * 256 + threadIdx.x;
    if (j >= RES * RES) return;
    const int bg = blockIdx.y;
    const float* x = X3 + bg * 8 * 512;

    float acc[8];
    float bj = b4[j];
#pragma unroll
    for (int b = 0; b < 8; ++b) acc[b] = bj;

    for (int k0 = 0; k0 < 512; k0 += 8) {
        float w[8];
#pragma unroll
        for (int u = 0; u < 8; ++u)
            w[u] = W4[(k0 + u) * (RES * RES) + j];
#pragma unroll
        for (int u = 0; u < 8; ++u) {
#pragma unroll
            for (int b = 0; b < 8; ++b)
                acc[b] = fmaf(x[b * 512 + k0 + u], w[u], acc[b]);
        }
    }

    const int row = j / RES, col = j % RES;
    const int p = (row / 20) * 5 + (col / 20);
#pragma unroll
    for (int b = 0; b < 8; ++b) {
        int bb = bg * 8 + b;
        float base = 1.0f - pores[bb * 25 + p];
        cond[bb * RES * RES + j] = fmaxf(acc[b] + base, 0.01f);
    }
}

// ---------------- Jacobi: DPP + packed-fp32 ----------------
__device__ __forceinline__ float dpp_shr1(float old_v, float src) {  // lane i <- src[i-1]
    return __int_as_float(__builtin_amdgcn_update_dpp(
        __float_as_int(old_v), __float_as_int(src), 0x138, 0xf, 0xf, false));
}
__device__ __forceinline__ float dpp_shl1(float old_v, float src) {  // lane i <- src[i+1]
    return __int_as_float(__builtin_amdgcn_update_dpp(
        __float_as_int(old_v), __float_as_int(src), 0x130, 0xf, 0xf, false));
}

// One row update: Tnew = wN*nb + wS*sb + wA*{wlo,ehi} + wB*{hi,lo}
__device__ __forceinline__ vf2 jrow(vf2 nb, vf2 sb, vf2 c,
                                    vf2 wNr, vf2 wSr, vf2 wAr, vf2 wBr, bool fix49) {
    float lo = c.x, hi = c.y;
    float wlo = dpp_shr1(lo, hi);
    float ehi = dpp_shl1(hi, lo);
    ehi = fix49 ? hi : ehi;
    vf2 P1; P1.x = wlo; P1.y = ehi;
    vf2 TS; TS.x = hi;  TS.y = lo;
    return wNr * nb + wSr * sb + wAr * P1 + wBr * TS;
}

// Own-rows substep (R compile-time): writes top/bot rows to LDS slots.
template<int R>
__device__ __forceinline__ void substepT(vf2 nin, vf2 sin,
                                         const vf2* wN, const vf2* wS,
                                         const vf2* wA, const vf2* wB,
                                         const vf2* Tin, vf2* Tout, bool fix49,
                                         vf2* topptr, vf2* botptr) {
    Tout[0] = jrow(nin, Tin[1], Tin[0], wN[0], wS[0], wA[0], wB[0], fix49);
#pragma unroll
    for (int r = 1; r < R - 1; ++r)
        Tout[r] = jrow(Tin[r - 1], Tin[r + 1], Tin[r], wN[r], wS[r], wA[r], wB[r], fix49);
    Tout[R - 1] = jrow(Tin[R - 2], sin, Tin[R - 1],
                       wN[R - 1], wS[R - 1], wA[R - 1], wB[R - 1], fix49);
    *topptr = Tout[0];
    *botptr = Tout[R - 1];
}

// ---------------- legacy single-block jacobi (fallback if ws too small) ----------------
template<int R>
__device__ __forceinline__ void jstep(const vf2* __restrict__ nptr, const vf2* __restrict__ sptr,
                                      vf2* __restrict__ topptr, vf2* __restrict__ botptr,
                                      const vf2* wN, const vf2* wS,
                                      const vf2* wA, const vf2* wB,
                                      const vf2* Tin, vf2* Tout, bool fix49) {
    vf2 nval = *nptr;
    vf2 sval = *sptr;
#pragma unroll
    for (int r = 0; r < R; ++r) {
        vf2 nb = (r == 0)     ? nval : Tin[r - 1];
        vf2 sb = (r == R - 1) ? sval : Tin[r + 1];
        Tout[r] = jrow(nb, sb, Tin[r], wN[r], wS[r], wA[r], wB[r], fix49);
    }
    *topptr = Tout[0];
    *botptr = Tout[R - 1];
}

__global__ __launch_bounds__(1024) void jacobi(const float* __restrict__ cond,
                                               float* __restrict__ kappa_out) {
    __shared__ float kst[RES * RES];
    __shared__ float SA[34 * SLOTP];
    __shared__ float SB[34 * SLOTP];

    const int b   = blockIdx.x;
    const int tid = threadIdx.x;

    for (int i = tid; i < RES * RES; i += 1024)
        kst[i] = cond[b * RES * RES + i];
    if (tid < SLOTP) {
        SA[32 * SLOTP + tid] = 1.0f;  SA[33 * SLOTP + tid] = 0.0f;
        SB[32 * SLOTP + tid] = 1.0f;  SB[33 * SLOTP + tid] = 0.0f;
    }
    __syncthreads();

    const int w    = tid >> 6;
    const int lane = tid & 63;
    const int R    = (w < 4) ? 7 : 6;
    const int r0   = (w < 4) ? 7 * w : 28 + 6 * (w - 4);
    const int c0   = min(2 * lane, 98), c1 = c0 + 1;
    const int lane2 = 2 * lane;
    const bool fix49 = (lane == 49);

    vf2 wN[7], wS[7], wA[7], wB[7], T0[7], T1[7];

#pragma unroll
    for (int r = 0; r < 7; ++r) {
        if (r < R) {
            int i   = r0 + r;
            int in_ = i ? i - 1 : 0;
            int is_ = (i < RES - 1) ? i + 1 : RES - 1;
            int jw  = c0 ? c0 - 1 : 0;
            int je  = (c1 < RES - 1) ? c1 + 1 : RES - 1;
            float kc0 = kst[i * RES + c0], kc1 = kst[i * RES + c1];
            float kn0 = 0.5f * (kc0 + kst[in_ * RES + c0]);
            float kn1 = 0.5f * (kc1 + kst[in_ * RES + c1]);
            float ks0 = 0.5f * (kc0 + kst[is_ * RES + c0]);
            float ks1 = 0.5f * (kc1 + kst[is_ * RES + c1]);
            float kw0 = 0.5f * (kc0 + kst[i * RES + jw]);
            float kw1 = 0.5f * (kc1 + kc0);
            float ke0 = 0.5f * (kc0 + kc1);
            float ke1 = 0.5f * (kc1 + kst[i * RES + je]);
            float inv0 = 1.0f / (kn0 + ks0 + kw0 + ke0 + 1e-12f);
            float inv1 = 1.0f / (kn1 + ks1 + kw1 + ke1 + 1e-12f);
            wN[r].x = kn0 * inv0;  wN[r].y = kn1 * inv1;
            wS[r].x = ks0 * inv0;  wS[r].y = ks1 * inv1;
            wA[r].x = kw0 * inv0;  wA[r].y = ke1 * inv1;
            wB[r].x = ke0 * inv0;  wB[r].y = kw1 * inv1;
            float v = 1.0f - (float)i * (1.0f / (RES - 1));
            T0[r].x = v;  T0[r].y = v;
        }
    }

    vf2 bot0 = (w < 4) ? T0[6] : T0[5];
    *(vf2*)(SA + (2 * w) * SLOTP + lane2)     = T0[0];
    *(vf2*)(SA + (2 * w + 1) * SLOTP + lane2) = bot0;
    __syncthreads();

    const int nslot = (w == 0)  ? 32 : (2 * w - 1);
    const int sslot = (w == 15) ? 33 : (2 * w + 2);
    const int topsl = 2 * w;

    const vf2* SAn = (const vf2*)(SA + nslot * SLOTP + lane2);
    const vf2* SAs = (const vf2*)(SA + sslot * SLOTP + lane2);
    const vf2* SBn = (const vf2*)(SB + nslot * SLOTP + lane2);
    const vf2* SBs = (const vf2*)(SB + sslot * SLOTP + lane2);
    vf2* SAtop = (vf2*)(SA + topsl * SLOTP + lane2);
    vf2* SAbot = (vf2*)(SA + (topsl + 1) * SLOTP + lane2);
    vf2* SBtop = (vf2*)(SB + topsl * SLOTP + lane2);
    vf2* SBbot = (vf2*)(SB + (topsl + 1) * SLOTP + lane2);

    for (int it = 0; it < ITERS / 2; ++it) {
        if (w < 4) jstep<7>(SAn, SAs, SBtop, SBbot, wN, wS, wA, wB, T0, T1, fix49);
        else       jstep<6>(SAn, SAs, SBtop, SBbot, wN, wS, wA, wB, T0, T1, fix49);
        __syncthreads();
        if (w < 4) jstep<7>(SBn, SBs, SAtop, SAbot, wN, wS, wA, wB, T1, T0, fix49);
        else       jstep<6>(SBn, SBs, SAtop, SAbot, wN, wS, wA, wB, T1, T0, fix49);
        __syncthreads();
    }

    if (w == 0) {
        float s = 0.0f;
        if (lane < 50)
            s = kst[c0] * (1.0f - T0[0].x) + kst[c1] * (1.0f - T0[0].y);
        for (int off = 32; off; off >>= 1)
            s += __shfl_down(s, off);
        if (lane == 0) kappa_out[b] = 2.0f * s;
    }
}

// ---------------- jacobi4: 4 blocks per sample, depth-4 cross-block halo ----------------
// block = p*32 + s (keeps a sample's parts on one XCD under round-robin dispatch).
// Rows per wave: {4,3,3,3,3,3,2,4}. Edge waves (w0 north / w7 south) keep a 4-row
// halo in registers, redundantly update it (bit-identical arithmetic), and exchange
// refreshed halos with the neighbor block every 4 steps via global memory +
// release/acquire flags (agent scope), double-buffered by group parity.
__global__ __launch_bounds__(512) void jacobi4(const float* __restrict__ cond,
                                               float* __restrict__ kappa_out,
                                               float* __restrict__ haloDn,
                                               float* __restrict__ haloUp,
                                               int* __restrict__ flagDn,
                                               int* __restrict__ flagUp) {
    __shared__ float kst[35 * 100];
    __shared__ float SA[16 * SLOTP];
    __shared__ float SB[16 * SLOTP];

    const int blk = blockIdx.x;
    const int s   = blk & 31;
    const int p   = blk >> 5;              // part 0..3
    const int tid = threadIdx.x;
    const int R0  = 25 * p;
    const int kLo = (p == 0) ? 0 : R0 - 5;
    const int kHi = (p == 3) ? 99 : R0 + 29;
    const int nk  = (kHi - kLo + 1) * 100;

    for (int i = tid; i < nk; i += 512)
        kst[i] = cond[s * RES * RES + kLo * 100 + i];
    __syncthreads();

    const int w    = tid >> 6;
    const int lane = tid & 63;
    const int R    = (w == 0 || w == 7) ? 4 : (w == 6 ? 2 : 3);
    const int rb   = (w == 0) ? 0 : (w == 7) ? 21 : (w == 6) ? 19 : (1 + 3 * w);
    const int c0   = min(2 * lane, 98), c1 = c0 + 1;
    const int lane2 = 2 * lane;
    const bool fix49 = (lane == 49);
    const bool hasN = (w == 0 && p > 0);
    const bool hasS = (w == 7 && p < 3);

    // weight + initial-T helper (identical arithmetic to the legacy kernel)
    auto kat = [&](int gi, int c) { return kst[(gi - kLo) * 100 + c]; };
    auto mkw = [&](int gi, vf2& wn, vf2& ws_, vf2& wa, vf2& wb, vf2& t) {
        int in_ = gi ? gi - 1 : 0;
        int is_ = (gi < RES - 1) ? gi + 1 : RES - 1;
        int jw  = c0 ? c0 - 1 : 0;
        int je  = (c1 < RES - 1) ? c1 + 1 : RES - 1;
        float kc0 = kat(gi, c0), kc1 = kat(gi, c1);
        float kn0 = 0.5f * (kc0 + kat(in_, c0));
        float kn1 = 0.5f * (kc1 + kat(in_, c1));
        float ks0 = 0.5f * (kc0 + kat(is_, c0));
        float ks1 = 0.5f * (kc1 + kat(is_, c1));
        float kw0 = 0.5f * (kc0 + kat(gi, jw));
        float kw1 = 0.5f * (kc1 + kc0);
        float ke0 = 0.5f * (kc0 + kc1);
        float ke1 = 0.5f * (kc1 + kat(gi, je));
        float inv0 = 1.0f / (kn0 + ks0 + kw0 + ke0 + 1e-12f);
        float inv1 = 1.0f / (kn1 + ks1 + kw1 + ke1 + 1e-12f);
        wn  = mk2(kn0 * inv0, kn1 * inv1);
        ws_ = mk2(ks0 * inv0, ks1 * inv1);
        wa  = mk2(kw0 * inv0, ke1 * inv1);
        wb  = mk2(ke0 * inv0, kw1 * inv1);
        float v = 1.0f - (float)gi * (1.0f / (RES - 1));
        t = mk2(v, v);
    };

    vf2 wN[4], wS[4], wA[4], wB[4], T0[4], T1[4];
#pragma unroll
    for (int r = 0; r < 4; ++r)
        if (r < R) mkw(R0 + rb + r, wN[r], wS[r], wA[r], wB[r], T0[r]);

    vf2 hwN[4], hwS[4], hwA[4], hwB[4], hA[4], hB[4];   // north halo rows R0-4..R0-1
    vf2 gwN[4], gwS[4], gwA[4], gwB[4], gA[4], gB[4];   // south halo rows R0+25..R0+28
    if (hasN) {
#pragma unroll
        for (int i = 0; i < 4; ++i)
            mkw(R0 - 4 + i, hwN[i], hwS[i], hwA[i], hwB[i], hA[i]);
    }
    if (hasS) {
#pragma unroll
        for (int i = 0; i < 4; ++i)
            mkw(R0 + 25 + i, gwN[i], gwS[i], gwA[i], gwB[i], gA[i]);
    }

    // LDS wave-interface slots: wave w publishes top->slot 2w, bottom->slot 2w+1
    const int nsl = (w > 0) ? 2 * w - 1 : 0;
    const int ssl = (w < 7) ? 2 * w + 2 : 0;
    const vf2* AN = (const vf2*)(SA + nsl * SLOTP + lane2);
    const vf2* AS = (const vf2*)(SA + ssl * SLOTP + lane2);
    const vf2* BN = (const vf2*)(SB + nsl * SLOTP + lane2);
    const vf2* BS = (const vf2*)(SB + ssl * SLOTP + lane2);
    vf2* ATp = (vf2*)(SA + (2 * w) * SLOTP + lane2);
    vf2* ABt = (vf2*)(SA + (2 * w + 1) * SLOTP + lane2);
    vf2* BTp = (vf2*)(SB + (2 * w) * SLOTP + lane2);
    vf2* BBt = (vf2*)(SB + (2 * w + 1) * SLOTP + lane2);

    vf2 bot0 = (R == 4) ? T0[3] : (R == 3 ? T0[2] : T0[1]);
    *ATp = T0[0];
    *ABt = bot0;
    __syncthreads();

// one Jacobi substep (SUB = 0..3 within a group), incl. shrinking halo updates
#define SUBX(TI, TO, NSL, SSL, TPL, BPL, HIN, HOUT, GIN, GOUT, SUB)                              \
    {                                                                                            \
        vf2 nin, sin;                                                                            \
        if (w == 0) nin = (p == 0) ? mk2(1.0f, 1.0f) : HIN[3];                                   \
        else        nin = *NSL;                                                                  \
        if (w == 7) sin = (p == 3) ? mk2(0.0f, 0.0f) : GIN[0];                                   \
        else        sin = *SSL;                                                                  \
        if (hasN) {                                                                              \
            if (SUB < 1) HOUT[1] = jrow(HIN[0], HIN[2], HIN[1], hwN[1], hwS[1], hwA[1], hwB[1], fix49); \
            if (SUB < 2) HOUT[2] = jrow(HIN[1], HIN[3], HIN[2], hwN[2], hwS[2], hwA[2], hwB[2], fix49); \
            if (SUB < 3) HOUT[3] = jrow(HIN[2], TI[0],  HIN[3], hwN[3], hwS[3], hwA[3], hwB[3], fix49); \
        }                                                                                        \
        if (hasS) {                                                                              \
            if (SUB < 3) GOUT[0] = jrow(TI[3],  GIN[1], GIN[0], gwN[0], gwS[0], gwA[0], gwB[0], fix49); \
            if (SUB < 2) GOUT[1] = jrow(GIN[0], GIN[2], GIN[1], gwN[1], gwS[1], gwA[1], gwB[1], fix49); \
            if (SUB < 1) GOUT[2] = jrow(GIN[1], GIN[3], GIN[2], gwN[2], gwS[2], gwA[2], gwB[2], fix49); \
        }                                                                                        \
        if (w == 0 || w == 7) substepT<4>(nin, sin, wN, wS, wA, wB, TI, TO, fix49, TPL, BPL);    \
        else if (w == 6)      substepT<2>(nin, sin, wN, wS, wA, wB, TI, TO, fix49, TPL, BPL);    \
        else                  substepT<3>(nin, sin, wN, wS, wA, wB, TI, TO, fix49, TPL, BPL);    \
        __syncthreads();                                                                         \
    }

    for (int v = 0; v < NGROUPS; ++v) {
        // fetch neighbor halo version v (v=0 computed locally at init)
        if (v) {
            if (hasN) {
                int* f = flagDn + s * 3 + (p - 1);
                if (lane == 0)
                    while (__hip_atomic_load(f, __ATOMIC_RELAXED, __HIP_MEMORY_SCOPE_AGENT) < v) {}
                __builtin_amdgcn_fence(__ATOMIC_ACQUIRE, "agent");
                const float* buf = haloDn + (((s * 3 + (p - 1)) * 2) + (v & 1)) * 512;
#pragma unroll
                for (int i = 0; i < 4; ++i)
                    hA[i] = *(const vf2*)(buf + i * 128 + lane2);
            }
            if (hasS) {
                int* f = flagUp + s * 3 + p;
                if (lane == 0)
                    while (__hip_atomic_load(f, __ATOMIC_RELAXED, __HIP_MEMORY_SCOPE_AGENT) < v) {}
                __builtin_amdgcn_fence(__ATOMIC_ACQUIRE, "agent");
                const float* buf = haloUp + (((s * 3 + p) * 2) + (v & 1)) * 512;
#pragma unroll
                for (int i = 0; i < 4; ++i)
                    gA[i] = *(const vf2*)(buf + i * 128 + lane2);
            }
        }

        SUBX(T0, T1, AN, AS, BTp, BBt, hA, hB, gA, gB, 0)
        SUBX(T1, T0, BN, BS, ATp, ABt, hB, hA, gB, gA, 1)
        SUBX(T0, T1, AN, AS, BTp, BBt, hA, hB, gA, gB, 2)
        SUBX(T1, T0, BN, BS, ATp, ABt, hB, hA, gB, gA, 3)

        // publish own refreshed edge rows (version v+1) into parity slot
        if (v + 1 < NGROUPS) {
            const int par = (v + 1) & 1;
            if (hasS) {
                float* buf = haloDn + ((s * 3 + p) * 2 + par) * 512;
#pragma unroll
                for (int i = 0; i < 4; ++i)
                    *(vf2*)(buf + i * 128 + lane2) = T0[i];
                __builtin_amdgcn_fence(__ATOMIC_RELEASE, "agent");
                if (lane == 0)
                    __hip_atomic_store(flagDn + s * 3 + p, v + 1, __ATOMIC_RELAXED, __HIP_MEMORY_SCOPE_AGENT);
            }
            if (hasN) {
                float* buf = haloUp + ((s * 3 + (p - 1)) * 2 + par) * 512;
#pragma unroll
                for (int i = 0; i < 4; ++i)
                    *(vf2*)(buf + i * 128 + lane2) = T0[i];
                __builtin_amdgcn_fence(__ATOMIC_RELEASE, "agent");
                if (lane == 0)
                    __hip_atomic_store(flagUp + s * 3 + (p - 1), v + 1, __ATOMIC_RELAXED, __HIP_MEMORY_SCOPE_AGENT);
            }
        }
    }
#undef SUBX

    // kappa from row 0 (part 0 only)
    if (p == 0 && w == 0) {
        float sm = 0.0f;
        if (lane < 50)
            sm = kst[c0] * (1.0f - T0[0].x) + kst[c1] * (1.0f - T0[0].y);
        for (int off = 32; off; off >>= 1)
            sm += __shfl_down(sm, off);
        if (lane == 0) kappa_out[s] = 2.0f * sm;
    }
}

extern "C" void kernel_launch(void* const* d_in, const int* in_sizes, int n_in,
                              void* d_out, int out_size, void* d_ws, size_t ws_size,
                              hipStream_t stream) {
    (void)in_sizes; (void)n_in; (void)out_size;
    const float* pores = (const float*)d_in[0];
    const float* W1 = (const float*)d_in[1];
    const float* b1 = (const float*)d_in[2];
    const float* W2 = (const float*)d_in[3];
    const float* b2 = (const float*)d_in[4];
    const float* W3 = (const float*)d_in[5];
    const float* b3 = (const float*)d_in[6];
    const float* W4 = (const float*)d_in[7];
    const float* b4 = (const float*)d_in[8];

    float* x3 = (float*)d_ws;                       // 32*512 floats
    float* haloDn = x3 + 32 * 512;                  // 32*3*2*4*128 floats
    float* haloUp = haloDn + 32 * 3 * 2 * 4 * 128;  // same size
    int*   flagDn = (int*)(haloUp + 32 * 3 * 2 * 4 * 128);
    int*   flagUp = flagDn + 32 * 3;

    float* kappa = (float*)d_out;                   // 32
    float* cond  = kappa + 32;                      // 32*100*100

    const size_t need = (size_t)(32 * 512 + 2 * 32 * 3 * 2 * 4 * 128) * sizeof(float)
                      + (size_t)(32 * 3 * 2) * sizeof(int);

    mlp123<<<32, 256, 0, stream>>>(pores, W1, b1, W2, b2, W3, b3, x3);
    fc4_fused<<<dim3(40, 4), 256, 0, stream>>>(x3, W4, b4, pores, cond);

    if (ws_size >= need) {
        hipMemsetAsync(flagDn, 0, 32 * 3 * 2 * sizeof(int), stream);
        jacobi4<<<128, 512, 0, stream>>>(cond, kappa, haloDn, haloUp, flagDn, flagUp);
    } else {
        jacobi<<<32, 1024, 0, stream>>>(cond, kappa);
    }
}

// Round 4
// 676.903 us; speedup vs baseline: 2.3292x; 2.3292x over previous
//
#include <hip/hip_runtime.h>
#include <hip/hip_bf16.h>

#define RES   100
#define ITERS 1000
#define SLOTP 128            // floats per LDS boundary-row slot

typedef float vf2 __attribute__((ext_vector_type(2)));

// ---------------- fused MLP layers 1-3 ----------------
__global__ __launch_bounds__(256) void mlp123(const float* __restrict__ pores,
                                              const float* __restrict__ W1, const float* __restrict__ b1,
                                              const float* __restrict__ W2, const float* __restrict__ b2,
                                              const float* __restrict__ W3, const float* __restrict__ b3,
                                              float* __restrict__ x3out) {
    __shared__ float x1[128];
    __shared__ float x2[256];
    const int s = blockIdx.x, tid = threadIdx.x;

    if (tid < 128) {
        float acc = b1[tid];
#pragma unroll
        for (int k = 0; k < 25; ++k)
            acc = fmaf(pores[s * 25 + k], W1[k * 128 + tid], acc);
        x1[tid] = fmaxf(acc, 0.0f);
    }
    __syncthreads();

    {
        float acc = b2[tid];
#pragma unroll 8
        for (int k = 0; k < 128; ++k)
            acc = fmaf(x1[k], W2[k * 256 + tid], acc);
        x2[tid] = fmaxf(acc, 0.0f);
    }
    __syncthreads();

    {
        float a0 = b3[tid], a1 = b3[tid + 256];
#pragma unroll 8
        for (int k = 0; k < 256; ++k) {
            float xv = x2[k];
            a0 = fmaf(xv, W3[k * 512 + tid],       a0);
            a1 = fmaf(xv, W3[k * 512 + tid + 256], a1);
        }
        x3out[s * 512 + tid]       = fmaxf(a0, 0.0f);
        x3out[s * 512 + tid + 256] = fmaxf(a1, 0.0f);
    }
}

// ---------------- layer 4: gen + residual + clamp, ILP-pipelined ----------------
// grid (40, 4): 256 j's per WG, 8 samples per bg
__global__ __launch_bounds__(256) void fc4_fused(const float* __restrict__ X3,
                                                 const float* __restrict__ W4,
                                                 const float* __restrict__ b4,
                                                 const float* __restrict__ pores,
                                                 float* __restrict__ cond) {
    const int j = blockIdx.x * 256 + threadIdx.x;
    if (j >= RES * RES) return;
    const int bg = blockIdx.y;
    const float* x = X3 + bg * 8 * 512;      // uniform-address reads -> SMEM path

    float acc[8];
    float bj = b4[j];
#pragma unroll
    for (int b = 0; b < 8; ++b) acc[b] = bj;

    for (int k0 = 0; k0 < 512; k0 += 8) {
        float w[8];
#pragma unroll
        for (int u = 0; u < 8; ++u)
            w[u] = W4[(k0 + u) * (RES * RES) + j];
#pragma unroll
        for (int u = 0; u < 8; ++u) {
#pragma unroll
            for (int b = 0; b < 8; ++b)
                acc[b] = fmaf(x[b * 512 + k0 + u], w[u], acc[b]);
        }
    }

    const int row = j / RES, col = j % RES;
    const int p = (row / 20) * 5 + (col / 20);
#pragma unroll
    for (int b = 0; b < 8; ++b) {
        int bb = bg * 8 + b;
        float base = 1.0f - pores[bb * 25 + p];
        cond[bb * RES * RES + j] = fmaxf(acc[b] + base, 0.01f);
    }
}

// ---------------- Jacobi solve: DPP + packed-fp32 (v_pk_fma_f32) ----------------
__device__ __forceinline__ float dpp_shr1(float old_v, float src) {  // lane i <- src[i-1] (wave_shr1)
    return __int_as_float(__builtin_amdgcn_update_dpp(
        __float_as_int(old_v), __float_as_int(src), 0x138, 0xf, 0xf, false));
}
__device__ __forceinline__ float dpp_shl1(float old_v, float src) {  // lane i <- src[i+1] (wave_shl1)
    return __int_as_float(__builtin_amdgcn_update_dpp(
        __float_as_int(old_v), __float_as_int(src), 0x130, 0xf, 0xf, false));
}

// One row update: Tnew = wN*nb + wS*sb + wB*{hi,lo} + wA*{wlo,ehi}
// Packed core: 3 VOP3P instrs; the {hi,lo} swap is free via op_sel on src1.
// Cross-lane E/W term added as 2 scalar fmaf on the vf2 halves.
__device__ __forceinline__ vf2 jrow(vf2 nb, vf2 sb, vf2 c,
                                    vf2 wNr, vf2 wSr, vf2 wAr, vf2 wBr, bool fix49) {
    float lo = c.x, hi = c.y;
    float wlo = dpp_shr1(lo, hi);
    float ehi = dpp_shl1(hi, lo);
    ehi = fix49 ? hi : ehi;
    vf2 acc;
    asm("v_pk_mul_f32 %0, %1, %2\n\t"
        "v_pk_fma_f32 %0, %3, %4, %0\n\t"
        "v_pk_fma_f32 %0, %5, %6, %0 op_sel:[0,1,0] op_sel_hi:[1,0,1]"
        : "=&v"(acc)
        : "v"(wNr), "v"(nb), "v"(wSr), "v"(sb), "v"(wBr), "v"(c));
    acc.x = fmaf(wAr.x, wlo, acc.x);
    acc.y = fmaf(wAr.y, ehi, acc.y);
    return acc;
}

template<int R>
__device__ __forceinline__ void jstep(const vf2* __restrict__ nptr, const vf2* __restrict__ sptr,
                                      vf2* __restrict__ topptr, vf2* __restrict__ botptr,
                                      const vf2* wN, const vf2* wS,
                                      const vf2* wA, const vf2* wB,
                                      const vf2* Tin, vf2* Tout, bool fix49) {
    vf2 nval = *nptr;
    vf2 sval = *sptr;
#pragma unroll
    for (int r = 0; r < R; ++r) {
        vf2 nb = (r == 0)     ? nval : Tin[r - 1];
        vf2 sb = (r == R - 1) ? sval : Tin[r + 1];
        Tout[r] = jrow(nb, sb, Tin[r], wN[r], wS[r], wA[r], wB[r], fix49);
    }
    *topptr = Tout[0];
    *botptr = Tout[R - 1];
}

__global__ __launch_bounds__(1024) void jacobi(const float* __restrict__ cond,
                                               float* __restrict__ kappa_out) {
    __shared__ float kst[RES * RES];
    __shared__ float SA[34 * SLOTP];
    __shared__ float SB[34 * SLOTP];

    const int b   = blockIdx.x;
    const int tid = threadIdx.x;

    for (int i = tid; i < RES * RES; i += 1024)
        kst[i] = cond[b * RES * RES + i];
    if (tid < SLOTP) {
        SA[32 * SLOTP + tid] = 1.0f;  SA[33 * SLOTP + tid] = 0.0f;
        SB[32 * SLOTP + tid] = 1.0f;  SB[33 * SLOTP + tid] = 0.0f;
    }
    __syncthreads();

    const int w    = tid >> 6;
    const int lane = tid & 63;
    const int R    = (w < 4) ? 7 : 6;
    const int r0   = (w < 4) ? 7 * w : 28 + 6 * (w - 4);
    const int c0   = min(2 * lane, 98), c1 = c0 + 1;
    const int lane2 = 2 * lane;
    const bool fix49 = (lane == 49);

    vf2 wN[7], wS[7], wA[7], wB[7], T0[7], T1[7];

#pragma unroll
    for (int r = 0; r < 7; ++r) {
        if (r < R) {
            int i   = r0 + r;
            int in_ = i ? i - 1 : 0;
            int is_ = (i < RES - 1) ? i + 1 : RES - 1;
            int jw  = c0 ? c0 - 1 : 0;
            int je  = (c1 < RES - 1) ? c1 + 1 : RES - 1;
            float kc0 = kst[i * RES + c0], kc1 = kst[i * RES + c1];
            float kn0 = 0.5f * (kc0 + kst[in_ * RES + c0]);
            float kn1 = 0.5f * (kc1 + kst[in_ * RES + c1]);
            float ks0 = 0.5f * (kc0 + kst[is_ * RES + c0]);
            float ks1 = 0.5f * (kc1 + kst[is_ * RES + c1]);
            float kw0 = 0.5f * (kc0 + kst[i * RES + jw]);
            float kw1 = 0.5f * (kc1 + kc0);
            float ke0 = 0.5f * (kc0 + kc1);
            float ke1 = 0.5f * (kc1 + kst[i * RES + je]);
            float inv0 = 1.0f / (kn0 + ks0 + kw0 + ke0 + 1e-12f);
            float inv1 = 1.0f / (kn1 + ks1 + kw1 + ke1 + 1e-12f);
            wN[r].x = kn0 * inv0;  wN[r].y = kn1 * inv1;
            wS[r].x = ks0 * inv0;  wS[r].y = ks1 * inv1;
            wA[r].x = kw0 * inv0;  wA[r].y = ke1 * inv1;
            wB[r].x = ke0 * inv0;  wB[r].y = kw1 * inv1;
            float v = 1.0f - (float)i * (1.0f / (RES - 1));
            T0[r].x = v;  T0[r].y = v;
        }
    }

    // publish initial boundary rows into SA
    vf2 bot0 = (w < 4) ? T0[6] : T0[5];
    *(vf2*)(SA + (2 * w) * SLOTP + lane2)     = T0[0];
    *(vf2*)(SA + (2 * w + 1) * SLOTP + lane2) = bot0;
    __syncthreads();

    const int nslot = (w == 0)  ? 32 : (2 * w - 1);
    const int sslot = (w == 15) ? 33 : (2 * w + 2);
    const int topsl = 2 * w;

    const vf2* SAn = (const vf2*)(SA + nslot * SLOTP + lane2);
    const vf2* SAs = (const vf2*)(SA + sslot * SLOTP + lane2);
    const vf2* SBn = (const vf2*)(SB + nslot * SLOTP + lane2);
    const vf2* SBs = (const vf2*)(SB + sslot * SLOTP + lane2);
    vf2* SAtop = (vf2*)(SA + topsl * SLOTP + lane2);
    vf2* SAbot = (vf2*)(SA + (topsl + 1) * SLOTP + lane2);
    vf2* SBtop = (vf2*)(SB + topsl * SLOTP + lane2);
    vf2* SBbot = (vf2*)(SB + (topsl + 1) * SLOTP + lane2);

    for (int it = 0; it < ITERS / 2; ++it) {
        if (w < 4) jstep<7>(SAn, SAs, SBtop, SBbot, wN, wS, wA, wB, T0, T1, fix49);
        else       jstep<6>(SAn, SAs, SBtop, SBbot, wN, wS, wA, wB, T0, T1, fix49);
        __syncthreads();
        if (w < 4) jstep<7>(SBn, SBs, SAtop, SAbot, wN, wS, wA, wB, T1, T0, fix49);
        else       jstep<6>(SBn, SBs, SAtop, SAbot, wN, wS, wA, wB, T1, T0, fix49);
        __syncthreads();
    }

    // kappa = mean_j 2*res*k[0][j]*(1 - T[0][j]) = 2 * sum_lanes k*(1-T)
    if (w == 0) {
        float s = 0.0f;
        if (lane < 50)
            s = kst[c0] * (1.0f - T0[0].x) + kst[c1] * (1.0f - T0[0].y);
        for (int off = 32; off; off >>= 1)
            s += __shfl_down(s, off);
        if (lane == 0) kappa_out[b] = 2.0f * s;
    }
}

extern "C" void kernel_launch(void* const* d_in, const int* in_sizes, int n_in,
                              void* d_out, int out_size, void* d_ws, size_t ws_size,
                              hipStream_t stream) {
    (void)in_sizes; (void)n_in; (void)out_size; (void)ws_size;
    const float* pores = (const float*)d_in[0];
    const float* W1 = (const float*)d_in[1];
    const float* b1 = (const float*)d_in[2];
    const float* W2 = (const float*)d_in[3];
    const float* b2 = (const float*)d_in[4];
    const float* W3 = (const float*)d_in[5];
    const float* b3 = (const float*)d_in[6];
    const float* W4 = (const float*)d_in[7];
    const float* b4 = (const float*)d_in[8];

    float* x3 = (float*)d_ws;               // 32*512

    float* kappa = (float*)d_out;           // 32
    float* cond  = kappa + 32;              // 32*100*100

    mlp123<<<32, 256, 0, stream>>>(pores, W1, b1, W2, b2, W3, b3, x3);
    fc4_fused<<<dim3(40, 4), 256, 0, stream>>>(x3, W4, b4, pores, cond);
    jacobi<<<32, 1024, 0, stream>>>(cond, kappa);
}

// Round 6
// 674.763 us; speedup vs baseline: 2.3366x; 1.0032x over previous
//
#include <hip/hip_runtime.h>
#include <hip/hip_bf16.h>

#define RES   100
#define ITERS 1000
#define SLOTP 128            // floats per LDS boundary-row slot

typedef float vf2 __attribute__((ext_vector_type(2)));

// ---------------- fused MLP layers 1-3 (outputs x3 TRANSPOSED: [k][b]) ----------------
__global__ __launch_bounds__(256) void mlp123(const float* __restrict__ pores,
                                              const float* __restrict__ W1, const float* __restrict__ b1,
                                              const float* __restrict__ W2, const float* __restrict__ b2,
                                              const float* __restrict__ W3, const float* __restrict__ b3,
                                              float* __restrict__ x3t) {
    __shared__ float x1[128];
    __shared__ float x2[256];
    const int s = blockIdx.x, tid = threadIdx.x;

    if (tid < 128) {
        float acc = b1[tid];
#pragma unroll
        for (int k = 0; k < 25; ++k)
            acc = fmaf(pores[s * 25 + k], W1[k * 128 + tid], acc);
        x1[tid] = fmaxf(acc, 0.0f);
    }
    __syncthreads();

    {
        float acc = b2[tid];
#pragma unroll 8
        for (int k = 0; k < 128; ++k)
            acc = fmaf(x1[k], W2[k * 256 + tid], acc);
        x2[tid] = fmaxf(acc, 0.0f);
    }
    __syncthreads();

    {
        float a0 = b3[tid], a1 = b3[tid + 256];
#pragma unroll 8
        for (int k = 0; k < 256; ++k) {
            float xv = x2[k];
            a0 = fmaf(xv, W3[k * 512 + tid],       a0);
            a1 = fmaf(xv, W3[k * 512 + tid + 256], a1);
        }
        // transposed store: x3t[k*32 + s]
        x3t[tid * 32 + s]         = fmaxf(a0, 0.0f);
        x3t[(tid + 256) * 32 + s] = fmaxf(a1, 0.0f);
    }
}

// ---------------- layer 4: gen + residual + clamp ----------------
// grid 79 × 256 threads. Block covers 128 j's (2 j-subtiles × 2 b-halves per wave).
// Each lane: 1 j, 16 samples, full k=512 chain (ascending k -> bit-identical to ref order).
// W4 read ONCE total (20 MB); x3t reads are wave-uniform (scalar path).
__global__ __launch_bounds__(256) void fc4_fused(const float* __restrict__ X3T,
                                                 const float* __restrict__ W4,
                                                 const float* __restrict__ b4,
                                                 const float* __restrict__ pores,
                                                 float* __restrict__ cond) {
    const int w    = threadIdx.x >> 6;
    const int lane = threadIdx.x & 63;
    const int jsub = w & 1;
    const int bh   = __builtin_amdgcn_readfirstlane(w >> 1);   // 0 or 1 (SGPR)
    const int j    = blockIdx.x * 128 + jsub * 64 + lane;
    if (j >= RES * RES) return;
    const int b0 = bh * 16;

    float acc[16];
    float bj = b4[j];
#pragma unroll
    for (int b = 0; b < 16; ++b) acc[b] = bj;

    const float* __restrict__ xt = X3T + b0;   // xt[k*32 + u], u<16: wave-uniform addr

    for (int k0 = 0; k0 < 512; k0 += 16) {
        float wv[16];
#pragma unroll
        for (int u = 0; u < 16; ++u)
            wv[u] = W4[(k0 + u) * (RES * RES) + j];
#pragma unroll
        for (int u = 0; u < 16; ++u) {
#pragma unroll
            for (int b = 0; b < 16; ++b)
                acc[b] = fmaf(wv[u], xt[(k0 + u) * 32 + b], acc[b]);
        }
    }

    const int row = j / RES, col = j % RES;
    const int p = (row / 20) * 5 + (col / 20);
#pragma unroll
    for (int b = 0; b < 16; ++b) {
        int bb = b0 + b;
        float base = 1.0f - pores[bb * 25 + p];
        cond[bb * RES * RES + j] = fmaxf(acc[b] + base, 0.01f);
    }
}

// ---------------- Jacobi solve: DPP + packed-fp32 (round-0 jrow, interior-first) -------
__device__ __forceinline__ float dpp_shr1(float old_v, float src) {  // lane i <- src[i-1]
    return __int_as_float(__builtin_amdgcn_update_dpp(
        __float_as_int(old_v), __float_as_int(src), 0x138, 0xf, 0xf, false));
}
__device__ __forceinline__ float dpp_shl1(float old_v, float src) {  // lane i <- src[i+1]
    return __int_as_float(__builtin_amdgcn_update_dpp(
        __float_as_int(old_v), __float_as_int(src), 0x130, 0xf, 0xf, false));
}

// Round-0 expression (compiler-scheduled; proven best codegen).
__device__ __forceinline__ vf2 jrow(vf2 nb, vf2 sb, vf2 c,
                                    vf2 wNr, vf2 wSr, vf2 wAr, vf2 wBr, bool fix49) {
    float lo = c.x, hi = c.y;
    float wlo = dpp_shr1(lo, hi);
    float ehi = dpp_shl1(hi, lo);
    ehi = fix49 ? hi : ehi;
    vf2 P1; P1.x = wlo; P1.y = ehi;
    vf2 TS; TS.x = hi;  TS.y = lo;
    return wNr * nb + wSr * sb + wAr * P1 + wBr * TS;
}

// Interior rows first: the post-barrier ds_read latency of nval/sval hides
// under R-2 register-only row updates.
template<int R>
__device__ __forceinline__ void jstep(const vf2* __restrict__ nptr, const vf2* __restrict__ sptr,
                                      vf2* __restrict__ topptr, vf2* __restrict__ botptr,
                                      const vf2* wN, const vf2* wS,
                                      const vf2* wA, const vf2* wB,
                                      const vf2* Tin, vf2* Tout, bool fix49) {
    vf2 nval = *nptr;
    vf2 sval = *sptr;
#pragma unroll
    for (int r = 1; r < R - 1; ++r)
        Tout[r] = jrow(Tin[r - 1], Tin[r + 1], Tin[r], wN[r], wS[r], wA[r], wB[r], fix49);
    Tout[0] = jrow(nval, Tin[1], Tin[0], wN[0], wS[0], wA[0], wB[0], fix49);
    *topptr = Tout[0];
    Tout[R - 1] = jrow(Tin[R - 2], sval, Tin[R - 1],
                       wN[R - 1], wS[R - 1], wA[R - 1], wB[R - 1], fix49);
    *botptr = Tout[R - 1];
}

__global__ __launch_bounds__(1024) void jacobi(const float* __restrict__ cond,
                                               float* __restrict__ kappa_out) {
    __shared__ float kst[RES * RES];
    __shared__ float SA[34 * SLOTP];
    __shared__ float SB[34 * SLOTP];

    const int b   = blockIdx.x;
    const int tid = threadIdx.x;

    for (int i = tid; i < RES * RES; i += 1024)
        kst[i] = cond[b * RES * RES + i];
    if (tid < SLOTP) {
        SA[32 * SLOTP + tid] = 1.0f;  SA[33 * SLOTP + tid] = 0.0f;
        SB[32 * SLOTP + tid] = 1.0f;  SB[33 * SLOTP + tid] = 0.0f;
    }
    __syncthreads();

    const int w    = tid >> 6;
    const int lane = tid & 63;
    const int R    = (w < 4) ? 7 : 6;
    const int r0   = (w < 4) ? 7 * w : 28 + 6 * (w - 4);
    const int c0   = min(2 * lane, 98), c1 = c0 + 1;
    const int lane2 = 2 * lane;
    const bool fix49 = (lane == 49);

    vf2 wN[7], wS[7], wA[7], wB[7], T0[7], T1[7];

#pragma unroll
    for (int r = 0; r < 7; ++r) {
        if (r < R) {
            int i   = r0 + r;
            int in_ = i ? i - 1 : 0;
            int is_ = (i < RES - 1) ? i + 1 : RES - 1;
            int jw  = c0 ? c0 - 1 : 0;
            int je  = (c1 < RES - 1) ? c1 + 1 : RES - 1;
            float kc0 = kst[i * RES + c0], kc1 = kst[i * RES + c1];
            float kn0 = 0.5f * (kc0 + kst[in_ * RES + c0]);
            float kn1 = 0.5f * (kc1 + kst[in_ * RES + c1]);
            float ks0 = 0.5f * (kc0 + kst[is_ * RES + c0]);
            float ks1 = 0.5f * (kc1 + kst[is_ * RES + c1]);
            float kw0 = 0.5f * (kc0 + kst[i * RES + jw]);
            float kw1 = 0.5f * (kc1 + kc0);
            float ke0 = 0.5f * (kc0 + kc1);
            float ke1 = 0.5f * (kc1 + kst[i * RES + je]);
            float inv0 = 1.0f / (kn0 + ks0 + kw0 + ke0 + 1e-12f);
            float inv1 = 1.0f / (kn1 + ks1 + kw1 + ke1 + 1e-12f);
            wN[r].x = kn0 * inv0;  wN[r].y = kn1 * inv1;
            wS[r].x = ks0 * inv0;  wS[r].y = ks1 * inv1;
            wA[r].x = kw0 * inv0;  wA[r].y = ke1 * inv1;
            wB[r].x = ke0 * inv0;  wB[r].y = kw1 * inv1;
            float v = 1.0f - (float)i * (1.0f / (RES - 1));
            T0[r].x = v;  T0[r].y = v;
        }
    }

    // publish initial boundary rows into SA
    vf2 bot0 = (w < 4) ? T0[6] : T0[5];
    *(vf2*)(SA + (2 * w) * SLOTP + lane2)     = T0[0];
    *(vf2*)(SA + (2 * w + 1) * SLOTP + lane2) = bot0;
    __syncthreads();

    const int nslot = (w == 0)  ? 32 : (2 * w - 1);
    const int sslot = (w == 15) ? 33 : (2 * w + 2);
    const int topsl = 2 * w;

    const vf2* SAn = (const vf2*)(SA + nslot * SLOTP + lane2);
    const vf2* SAs = (const vf2*)(SA + sslot * SLOTP + lane2);
    const vf2* SBn = (const vf2*)(SB + nslot * SLOTP + lane2);
    const vf2* SBs = (const vf2*)(SB + sslot * SLOTP + lane2);
    vf2* SAtop = (vf2*)(SA + topsl * SLOTP + lane2);
    vf2* SAbot = (vf2*)(SA + (topsl + 1) * SLOTP + lane2);
    vf2* SBtop = (vf2*)(SB + topsl * SLOTP + lane2);
    vf2* SBbot = (vf2*)(SB + (topsl + 1) * SLOTP + lane2);

    for (int it = 0; it < ITERS / 2; ++it) {
        if (w < 4) jstep<7>(SAn, SAs, SBtop, SBbot, wN, wS, wA, wB, T0, T1, fix49);
        else       jstep<6>(SAn, SAs, SBtop, SBbot, wN, wS, wA, wB, T0, T1, fix49);
        __syncthreads();
        if (w < 4) jstep<7>(SBn, SBs, SAtop, SAbot, wN, wS, wA, wB, T1, T0, fix49);
        else       jstep<6>(SBn, SBs, SAtop, SAbot, wN, wS, wA, wB, T1, T0, fix49);
        __syncthreads();
    }

    // kappa = mean_j 2*res*k[0][j]*(1 - T[0][j]) = 2 * sum_lanes k*(1-T)
    if (w == 0) {
        float s = 0.0f;
        if (lane < 50)
            s = kst[c0] * (1.0f - T0[0].x) + kst[c1] * (1.0f - T0[0].y);
        for (int off = 32; off; off >>= 1)
            s += __shfl_down(s, off);
        if (lane == 0) kappa_out[b] = 2.0f * s;
    }
}

extern "C" void kernel_launch(void* const* d_in, const int* in_sizes, int n_in,
                              void* d_out, int out_size, void* d_ws, size_t ws_size,
                              hipStream_t stream) {
    (void)in_sizes; (void)n_in; (void)out_size; (void)ws_size;
    const float* pores = (const float*)d_in[0];
    const float* W1 = (const float*)d_in[1];
    const float* b1 = (const float*)d_in[2];
    const float* W2 = (const float*)d_in[3];
    const float* b2 = (const float*)d_in[4];
    const float* W3 = (const float*)d_in[5];
    const float* b3 = (const float*)d_in[6];
    const float* W4 = (const float*)d_in[7];
    const float* b4 = (const float*)d_in[8];

    float* x3t = (float*)d_ws;              // 512*32 floats, [k][b] layout

    float* kappa = (float*)d_out;           // 32
    float* cond  = kappa + 32;              // 32*100*100

    mlp123<<<32, 256, 0, stream>>>(pores, W1, b1, W2, b2, W3, b3, x3t);
    fc4_fused<<<79, 256, 0, stream>>>(x3t, W4, b4, pores, cond);
    jacobi<<<32, 1024, 0, stream>>>(cond, kappa);
}

// Round 7
// 545.118 us; speedup vs baseline: 2.8923x; 1.2378x over previous
//
#include <hip/hip_runtime.h>
#include <hip/hip_bf16.h>

#define RES   100
#define ITERS 1000
#define SLOTP 128            // floats per LDS boundary-column slot

typedef float vf2 __attribute__((ext_vector_type(2)));

// ---------------- fused MLP layers 1-3 (round-0 exact) ----------------
__global__ __launch_bounds__(256) void mlp123(const float* __restrict__ pores,
                                              const float* __restrict__ W1, const float* __restrict__ b1,
                                              const float* __restrict__ W2, const float* __restrict__ b2,
                                              const float* __restrict__ W3, const float* __restrict__ b3,
                                              float* __restrict__ x3out) {
    __shared__ float x1[128];
    __shared__ float x2[256];
    const int s = blockIdx.x, tid = threadIdx.x;

    if (tid < 128) {
        float acc = b1[tid];
#pragma unroll
        for (int k = 0; k < 25; ++k)
            acc = fmaf(pores[s * 25 + k], W1[k * 128 + tid], acc);
        x1[tid] = fmaxf(acc, 0.0f);
    }
    __syncthreads();

    {
        float acc = b2[tid];
#pragma unroll 8
        for (int k = 0; k < 128; ++k)
            acc = fmaf(x1[k], W2[k * 256 + tid], acc);
        x2[tid] = fmaxf(acc, 0.0f);
    }
    __syncthreads();

    {
        float a0 = b3[tid], a1 = b3[tid + 256];
#pragma unroll 8
        for (int k = 0; k < 256; ++k) {
            float xv = x2[k];
            a0 = fmaf(xv, W3[k * 512 + tid],       a0);
            a1 = fmaf(xv, W3[k * 512 + tid + 256], a1);
        }
        x3out[s * 512 + tid]       = fmaxf(a0, 0.0f);
        x3out[s * 512 + tid + 256] = fmaxf(a1, 0.0f);
    }
}

// ---------------- layer 4 (round-0 exact): gen + residual + clamp ----------------
__global__ __launch_bounds__(256) void fc4_fused(const float* __restrict__ X3,
                                                 const float* __restrict__ W4,
                                                 const float* __restrict__ b4,
                                                 const float* __restrict__ pores,
                                                 float* __restrict__ cond) {
    const int j = blockIdx.x * 256 + threadIdx.x;
    if (j >= RES * RES) return;
    const int bg = blockIdx.y;
    const float* x = X3 + bg * 8 * 512;      // uniform-address reads -> SMEM path

    float acc[8];
    float bj = b4[j];
#pragma unroll
    for (int b = 0; b < 8; ++b) acc[b] = bj;

    for (int k0 = 0; k0 < 512; k0 += 8) {
        float w[8];
#pragma unroll
        for (int u = 0; u < 8; ++u)
            w[u] = W4[(k0 + u) * (RES * RES) + j];
#pragma unroll
        for (int u = 0; u < 8; ++u) {
#pragma unroll
            for (int b = 0; b < 8; ++b)
                acc[b] = fmaf(x[b * 512 + k0 + u], w[u], acc[b]);
        }
    }

    const int row = j / RES, col = j % RES;
    const int p = (row / 20) * 5 + (col / 20);
#pragma unroll
    for (int b = 0; b < 8; ++b) {
        int bb = bg * 8 + b;
        float base = 1.0f - pores[bb * 25 + p];
        cond[bb * RES * RES + j] = fmaxf(acc[b] + base, 0.01f);
    }
}

// ---------------- Jacobi solve: TRANSPOSED layout ----------------
// Lanes span ROWS (Dirichlet axis): lane l holds rows (2l, 2l+1) packed in vf2.
// Waves span COLUMNS: wave w owns R columns (4 waves x 7 + 12 waves x 6 = 100).
// N/S neighbors: in-lane swap + DPP (bound_ctrl=1, no old_v movs).
// Virtual Dirichlet rows: constant seed C (pk_mul -> pk_fma), edge DPP weight zeroed.
// E/W (Neumann) columns: LDS slot exchange; edge waves read their OWN slot.
__device__ __forceinline__ float dpp_shr1_z(float src) {  // lane l <- src[l-1], OOB -> 0
    return __int_as_float(__builtin_amdgcn_update_dpp(
        0, __float_as_int(src), 0x138, 0xf, 0xf, true));
}
__device__ __forceinline__ float dpp_shl1_z(float src) {  // lane l <- src[l+1], OOB -> 0
    return __int_as_float(__builtin_amdgcn_update_dpp(
        0, __float_as_int(src), 0x130, 0xf, 0xf, true));
}

// c = {T[i0,col], T[i1,col]}; wv/ev = west/east column vf2.
// P  = {north-of-lo, south-of-hi} (DPP), TS = {hi, lo} (in-lane N/S).
// .x order: C + kN*N + kS*S + kW*W + kE*E  == reference order.
__device__ __forceinline__ vf2 jrowT(vf2 wv, vf2 ev, vf2 c,
                                     vf2 wWr, vf2 wEr, vf2 wPr, vf2 wTr, vf2 Cr) {
    float nlo = dpp_shr1_z(c.y);
    float shi = dpp_shl1_z(c.x);
    vf2 P;  P.x  = nlo; P.y  = shi;
    vf2 TS; TS.x = c.y; TS.y = c.x;
    return Cr + wPr * P + wTr * TS + wWr * wv + wEr * ev;
}

template<int R>
__device__ __forceinline__ void jstepT(const vf2* __restrict__ wptr, const vf2* __restrict__ eptr,
                                       vf2* __restrict__ topptr, vf2* __restrict__ botptr,
                                       const vf2* wW, const vf2* wE,
                                       const vf2* wP, const vf2* wT, const vf2* C,
                                       const vf2* Tin, vf2* Tout) {
    vf2 wval = *wptr;
    vf2 eval = *eptr;
#pragma unroll
    for (int r = 0; r < R; ++r) {
        vf2 wv = (r == 0)     ? wval : Tin[r - 1];
        vf2 ev = (r == R - 1) ? eval : Tin[r + 1];
        Tout[r] = jrowT(wv, ev, Tin[r], wW[r], wE[r], wP[r], wT[r], C[r]);
    }
    *topptr = Tout[0];
    *botptr = Tout[R - 1];
}

__global__ __launch_bounds__(1024) void jacobi(const float* __restrict__ cond,
                                               float* __restrict__ kappa_out) {
    __shared__ float kst[RES * RES];
    __shared__ float SA[32 * SLOTP];
    __shared__ float SB[32 * SLOTP];
    __shared__ float red[16];

    const int b   = blockIdx.x;
    const int tid = threadIdx.x;

    for (int i = tid; i < RES * RES; i += 1024)
        kst[i] = cond[b * RES * RES + i];
    __syncthreads();

    const int w    = tid >> 6;
    const int lane = tid & 63;
    const int R    = (w < 4) ? 7 : 6;
    const int c0   = (w < 4) ? 7 * w : 28 + 6 * (w - 4);
    const int l    = min(lane, 49);
    const int i0   = 2 * l, i1 = 2 * l + 1;
    const int lane2 = 2 * lane;

    vf2 wW[7], wE[7], wP[7], wT[7], C[7], T0[7], T1[7];

#pragma unroll
    for (int r = 0; r < 7; ++r) {
        if (r < R) {
            int c  = c0 + r;
            int in_ = i0 ? i0 - 1 : 0;                 // north clamp (edge-pad k)
            int is_ = (i1 < RES - 1) ? i1 + 1 : RES - 1;
            int jw  = c ? c - 1 : 0;
            int je  = (c < RES - 1) ? c + 1 : RES - 1;
            float kc0 = kst[i0 * RES + c], kc1 = kst[i1 * RES + c];
            float kn0 = 0.5f * (kc0 + kst[in_ * RES + c]);
            float ks0 = 0.5f * (kc0 + kc1);            // south of i0 = i1
            float kw0 = 0.5f * (kc0 + kst[i0 * RES + jw]);
            float ke0 = 0.5f * (kc0 + kst[i0 * RES + je]);
            float kn1 = 0.5f * (kc1 + kc0);            // north of i1 = i0
            float ks1 = 0.5f * (kc1 + kst[is_ * RES + c]);
            float kw1 = 0.5f * (kc1 + kst[i1 * RES + jw]);
            float ke1 = 0.5f * (kc1 + kst[i1 * RES + je]);
            float inv0 = 1.0f / (kn0 + ks0 + kw0 + ke0 + 1e-12f);
            float inv1 = 1.0f / (kn1 + ks1 + kw1 + ke1 + 1e-12f);
            wW[r].x = kw0 * inv0;  wW[r].y = kw1 * inv1;
            wE[r].x = ke0 * inv0;  wE[r].y = ke1 * inv1;
            // P = {N-of-lo (DPP), S-of-hi (DPP)}: zero weight on virtual-edge lanes
            wP[r].x = (l == 0)  ? 0.0f : kn0 * inv0;
            wP[r].y = (l >= 49) ? 0.0f : ks1 * inv1;
            // TS = {S-of-lo = hi, N-of-hi = lo}
            wT[r].x = ks0 * inv0;  wT[r].y = kn1 * inv1;
            // constant seed: virtual north row (T=1) for lane 0; virtual south (T=0) adds 0
            C[r].x = (l == 0) ? kn0 * inv0 : 0.0f;
            C[r].y = 0.0f;
            T0[r].x = 1.0f - (float)i0 * (1.0f / (RES - 1));
            T0[r].y = 1.0f - (float)i1 * (1.0f / (RES - 1));
        }
    }

    // publish initial boundary columns into SA
    vf2 bot0 = (w < 4) ? T0[6] : T0[5];
    *(vf2*)(SA + (2 * w) * SLOTP + lane2)     = T0[0];
    *(vf2*)(SA + (2 * w + 1) * SLOTP + lane2) = bot0;
    __syncthreads();

    // west input: west-neighbor's bot slot; wave 0 reads its OWN top (Neumann self)
    // east input: east-neighbor's top slot; wave 15 reads its OWN bot
    const int wslot = (w == 0)  ? 0  : (2 * w - 1);
    const int eslot = (w == 15) ? 31 : (2 * w + 2);
    const int topsl = 2 * w;

    const vf2* SAw = (const vf2*)(SA + wslot * SLOTP + lane2);
    const vf2* SAe = (const vf2*)(SA + eslot * SLOTP + lane2);
    const vf2* SBw = (const vf2*)(SB + wslot * SLOTP + lane2);
    const vf2* SBe = (const vf2*)(SB + eslot * SLOTP + lane2);
    vf2* SAtop = (vf2*)(SA + topsl * SLOTP + lane2);
    vf2* SAbot = (vf2*)(SA + (topsl + 1) * SLOTP + lane2);
    vf2* SBtop = (vf2*)(SB + topsl * SLOTP + lane2);
    vf2* SBbot = (vf2*)(SB + (topsl + 1) * SLOTP + lane2);

    for (int it = 0; it < ITERS / 2; ++it) {
        if (w < 4) jstepT<7>(SAw, SAe, SBtop, SBbot, wW, wE, wP, wT, C, T0, T1);
        else       jstepT<6>(SAw, SAe, SBtop, SBbot, wW, wE, wP, wT, C, T0, T1);
        __syncthreads();
        if (w < 4) jstepT<7>(SBw, SBe, SAtop, SAbot, wW, wE, wP, wT, C, T1, T0);
        else       jstepT<6>(SBw, SBe, SAtop, SAbot, wW, wE, wP, wT, C, T1, T0);
        __syncthreads();
    }

    // kappa = 2 * sum_j k[0][j]*(1 - T[0][j]); row 0 lives in lane 0's .x
    if (lane == 0) {
        float part = 0.0f;
#pragma unroll
        for (int r = 0; r < 7; ++r)
            if (r < R) part = fmaf(kst[c0 + r], 1.0f - T0[r].x, part);
        red[w] = part;
    }
    __syncthreads();
    if (tid == 0) {
        float s = 0.0f;
#pragma unroll
        for (int i = 0; i < 16; ++i) s += red[i];
        kappa_out[b] = 2.0f * s;
    }
}

extern "C" void kernel_launch(void* const* d_in, const int* in_sizes, int n_in,
                              void* d_out, int out_size, void* d_ws, size_t ws_size,
                              hipStream_t stream) {
    (void)in_sizes; (void)n_in; (void)out_size; (void)ws_size;
    const float* pores = (const float*)d_in[0];
    const float* W1 = (const float*)d_in[1];
    const float* b1 = (const float*)d_in[2];
    const float* W2 = (const float*)d_in[3];
    const float* b2 = (const float*)d_in[4];
    const float* W3 = (const float*)d_in[5];
    const float* b3 = (const float*)d_in[6];
    const float* W4 = (const float*)d_in[7];
    const float* b4 = (const float*)d_in[8];

    float* x3 = (float*)d_ws;               // 32*512

    float* kappa = (float*)d_out;           // 32
    float* cond  = kappa + 32;              // 32*100*100

    mlp123<<<32, 256, 0, stream>>>(pores, W1, b1, W2, b2, W3, b3, x3);
    fc4_fused<<<dim3(40, 4), 256, 0, stream>>>(x3, W4, b4, pores, cond);
    jacobi<<<32, 1024, 0, stream>>>(cond, kappa);
}